// Round 6
// baseline (160.490 us; speedup 1.0000x reference)
//
#include <hip/hip_runtime.h>
#include <stdint.h>

typedef unsigned int u32;
typedef unsigned long long u64;

#define BB 8
#define NN 8192
#define CC 80
#define KK 1000
#define NC (NN*CC)            // 655360
#define MAXIDX (NC-1)
#define NMS_THR 0.5f
#define SCORE_THR 0.05f
#define MAX_RATIO 4.135166556742356f
#define CLS_OFF 10000.0f
#define CAP 2048
#define NW 16                 // u64 words per mask row
#define HB 8                  // hist sub-blocks per batch
#define GB 128                // gather blocks per batch
#define GSL 2048              // per-slice capacity (u64)

// ---- workspace layout (bytes) ----
#define WS_HIST    0          // BB*HB*2048*4 = 524288
#define WS_GCNT    524288     // BB*GB*4 = 4096
#define WS_TBOX    528384     // 128000
#define WS_TOBOX   656384     // 128000
#define WS_TSCORE  784384     // 32000
#define WS_TCLS    816384     // 32000
#define WS_TVALID  848384     // 32000
#define WS_MASK    880384     // 1024000 -> ends 1904384
#define WS_GSLICE  1904384    // BB*GB*GSL*8 = 16777216 -> ends 18681600

__device__ __forceinline__ u32 mapf(float f) {
    u32 u = __float_as_uint(f);
    return (u & 0x80000000u) ? ~u : (u | 0x80000000u);
}
__device__ __forceinline__ float unmapf(u32 m) {
    u32 u = (m & 0x80000000u) ? (m ^ 0x80000000u) : ~m;
    return __uint_as_float(u);
}

// ---------------- pass 1: per-sub-block private 11-bit histograms (no atomics, no init) ----
__global__ __launch_bounds__(1024) void hist0_pass(const float* __restrict__ scores,
                                                   u32* __restrict__ hist) {
    __shared__ u32 lh[2048];
    int b = blockIdx.y, blk = blockIdx.x;
    for (int i = threadIdx.x; i < 2048; i += 1024) lh[i] = 0;
    __syncthreads();
    const float4* sp = (const float4*)(scores + (size_t)b * NC);
    for (int v = blk * 1024 + threadIdx.x; v < NC / 4; v += HB * 1024) {
        float4 s4 = sp[v];
        float ss[4] = {s4.x, s4.y, s4.z, s4.w};
        #pragma unroll
        for (int q = 0; q < 4; ++q) {
            float s = ss[q] > SCORE_THR ? ss[q] : -1.0f;
            atomicAdd(&lh[mapf(s) >> 21], 1u);
        }
    }
    __syncthreads();
    u32* ho = hist + ((size_t)b * HB + blk) * 2048;
    for (int i = threadIdx.x; i < 2048; i += 1024) ho[i] = lh[i];
}

// 256-thread digit select over summed sub-hists (descending). bcast[0]=digit.
__device__ __forceinline__ void sel_digit_sum(const u32* __restrict__ h, u32 need,
                                              u32* suf, u32* bcast) {
    int t = threadIdx.x;
    u32 hv[8];
    u32 s = 0;
    #pragma unroll
    for (int q = 0; q < 8; ++q) {
        u32 v = 0;
        #pragma unroll
        for (int sb = 0; sb < HB; ++sb) v += h[sb * 2048 + t * 8 + q];
        hv[q] = v; s += v;
    }
    u32 grp = s;
    suf[t] = s;
    __syncthreads();
    #pragma unroll
    for (int off = 1; off < 256; off <<= 1) {
        u32 v = (t + off < 256) ? suf[t + off] : 0u;
        __syncthreads();
        suf[t] += v;
        __syncthreads();
    }
    u32 cumAbove = suf[t] - grp;
    if (cumAbove < need && suf[t] >= need) {
        u32 cum = cumAbove;
        int d = t * 8;
        for (int q = 7; q >= 0; --q) {
            if (cum + hv[q] >= need) { d = t * 8 + q; break; }
            cum += hv[q];
        }
        bcast[0] = (u32)d;
    }
    __syncthreads();
}

// ---------------- pass 2: gather boundary-bucket superset into per-block slices ----------
__global__ __launch_bounds__(256) void gather2(const float* __restrict__ scores,
                                               const u32* __restrict__ hist,
                                               u64* __restrict__ gslice,
                                               u32* __restrict__ gcnt) {
    __shared__ u32 suf[256];
    __shared__ u32 bcast[2];
    __shared__ u32 lpos;
    int b = blockIdx.y, blk = blockIdx.x;
    if (threadIdx.x == 0) lpos = 0;
    sel_digit_sum(hist + (size_t)b * HB * 2048, (u32)KK, suf, bcast);
    u32 d0 = bcast[0];
    u64* slice = gslice + ((size_t)b * GB + blk) * GSL;
    const float4* sp = (const float4*)(scores + (size_t)b * NC);
    for (int v = blk * 256 + threadIdx.x; v < NC / 4; v += GB * 256) {
        float4 s4 = sp[v];
        float ss[4] = {s4.x, s4.y, s4.z, s4.w};
        #pragma unroll
        for (int q = 0; q < 4; ++q) {
            float s = ss[q] > SCORE_THR ? ss[q] : -1.0f;
            u32 m = mapf(s);
            if ((m >> 21) >= d0) {
                u32 p = atomicAdd(&lpos, 1u);
                if (p < GSL) {
                    u32 idx = (u32)(v * 4 + q);
                    slice[p] = ((u64)m << 32) | (u64)(MAXIDX - idx);
                }
            }
        }
    }
    __syncthreads();
    if (threadIdx.x == 0) gcnt[b * GB + blk] = (lpos > GSL) ? (u32)GSL : lpos;
}

// ---------------- finalize: in-block exact select + sort + decode (1 block/batch) --------
__global__ __launch_bounds__(1024) void finalize(
    const u64* __restrict__ gslice, const u32* __restrict__ gcnt,
    const u32* __restrict__ hist,
    const float* __restrict__ rois, const float* __restrict__ reg,
    float* __restrict__ tbox, float* __restrict__ tobox,
    float* __restrict__ tscore, float* __restrict__ tcls, u32* __restrict__ tvalid) {
    __shared__ u32 h2[2048];
    __shared__ u32 sc[1024];
    __shared__ u32 bc[2];
    __shared__ u64 keys[CAP];
    __shared__ u32 lpos;
    int b = blockIdx.x;
    int t = threadIdx.x;
    int wid = t >> 6, lane = t & 63;
    const u64* slices = gslice + (size_t)b * GB * GSL;
    const u32* cnts = gcnt + b * GB;

    // Phase A: (d0, rem) from summed sub-hists; 2 bins/thread, descending order
    {
        const u32* h = hist + (size_t)b * HB * 2048;
        u32 hv0 = 0, hv1 = 0;
        #pragma unroll
        for (int sb = 0; sb < HB; ++sb) {
            hv0 += h[sb * 2048 + 2 * t];
            hv1 += h[sb * 2048 + 2 * t + 1];
        }
        u32 grp = hv0 + hv1;
        sc[t] = grp;
        __syncthreads();
        for (int off = 1; off < 1024; off <<= 1) {
            u32 v = (t + off < 1024) ? sc[t + off] : 0u;
            __syncthreads();
            sc[t] += v;
            __syncthreads();
        }
        u32 need = (u32)KK;
        u32 cumAbove = sc[t] - grp;
        if (cumAbove < need && sc[t] >= need) {
            if (cumAbove + hv1 >= need) { bc[0] = 2u * t + 1u; bc[1] = need - cumAbove; }
            else                        { bc[0] = 2u * t;      bc[1] = need - cumAbove - hv1; }
        }
        __syncthreads();
    }
    u32 d0 = bc[0], rem = bc[1];
    __syncthreads();

    // Phase B: 2048-bin hist of bits 20..10 for items with (m>>21)==d0
    for (int i = t; i < 2048; i += 1024) h2[i] = 0;
    __syncthreads();
    for (int s = wid; s < GB; s += 16) {
        int cnt = (int)cnts[s];
        const u64* sl = slices + (size_t)s * GSL;
        for (int i = lane; i < cnt; i += 64) {
            u32 m = (u32)(sl[i] >> 32);
            if ((m >> 21) == d0) atomicAdd(&h2[(m >> 10) & 0x7FFu], 1u);
        }
    }
    __syncthreads();
    // Phase C: (d1, rem1), need=rem
    {
        u32 hv0 = h2[2 * t], hv1 = h2[2 * t + 1];
        u32 grp = hv0 + hv1;
        sc[t] = grp;
        __syncthreads();
        for (int off = 1; off < 1024; off <<= 1) {
            u32 v = (t + off < 1024) ? sc[t + off] : 0u;
            __syncthreads();
            sc[t] += v;
            __syncthreads();
        }
        u32 cumAbove = sc[t] - grp;
        if (cumAbove < rem && sc[t] >= rem) {
            if (cumAbove + hv1 >= rem) { bc[0] = 2u * t + 1u; bc[1] = rem - cumAbove; }
            else                       { bc[0] = 2u * t;      bc[1] = rem - cumAbove - hv1; }
        }
        __syncthreads();
    }
    u32 d1 = bc[0], rem1 = bc[1];
    u32 top22 = (d0 << 11) | d1;
    __syncthreads();

    // Phase D: 1024-bin hist of low 10 bits for items with top 22 bits == top22
    for (int i = t; i < 1024; i += 1024) h2[i] = 0;
    __syncthreads();
    for (int s = wid; s < GB; s += 16) {
        int cnt = (int)cnts[s];
        const u64* sl = slices + (size_t)s * GSL;
        for (int i = lane; i < cnt; i += 64) {
            u32 m = (u32)(sl[i] >> 32);
            if ((m >> 10) == top22) atomicAdd(&h2[m & 0x3FFu], 1u);
        }
    }
    __syncthreads();
    // Phase E: d2, need=rem1 -> exact 32-bit s*
    {
        u32 grp = h2[t];
        sc[t] = grp;
        __syncthreads();
        for (int off = 1; off < 1024; off <<= 1) {
            u32 v = (t + off < 1024) ? sc[t + off] : 0u;
            __syncthreads();
            sc[t] += v;
            __syncthreads();
        }
        u32 cumAbove = sc[t] - grp;
        if (cumAbove < rem1 && sc[t] >= rem1) bc[0] = (u32)t;
        __syncthreads();
    }
    u32 sstar = (top22 << 10) | bc[0];

    // Phase F: gather all m >= s* into keys
    if (t == 0) lpos = 0;
    __syncthreads();
    for (int s = wid; s < GB; s += 16) {
        int cnt = (int)cnts[s];
        const u64* sl = slices + (size_t)s * GSL;
        for (int i = lane; i < cnt; i += 64) {
            u64 key = sl[i];
            if ((u32)(key >> 32) >= sstar) {
                u32 p = atomicAdd(&lpos, 1u);
                if (p < CAP) keys[p] = key;
            }
        }
    }
    __syncthreads();
    u32 kcnt = (lpos > CAP) ? (u32)CAP : lpos;
    for (int i = t; i < CAP; i += 1024) if (i >= (int)kcnt) keys[i] = 0ull;
    __syncthreads();

    // bitonic sort, descending
    for (int k = 2; k <= CAP; k <<= 1) {
        for (int j = k >> 1; j > 0; j >>= 1) {
            for (int i = t; i < CAP; i += 1024) {
                int ixj = i ^ j;
                if (ixj > i) {
                    u64 a = keys[i], c = keys[ixj];
                    bool desc = ((i & k) == 0);
                    if ((a < c) == desc) { keys[i] = c; keys[ixj] = a; }
                }
            }
            __syncthreads();
        }
    }

    // decode top-K
    for (int kk = t; kk < KK; kk += 1024) {
        u64 key = keys[kk];
        float score, cf, box0, box1, box2, box3;
        u32 vld;
        if (kk < (int)kcnt) {
            u32 m = (u32)(key >> 32);
            u32 idx = (u32)MAXIDX - (u32)(key & 0xFFFFFFFFu);
            score = unmapf(m);
            vld = (score > SCORE_THR) ? 1u : 0u;
            int n = idx / CC, c = idx % CC;
            cf = (float)(c + 1);
            const float* r = rois + ((size_t)b * NN + n) * 4;
            const float* d = reg  + ((size_t)b * NN + n) * 4;
            float x1 = r[0], y1 = r[1], x2 = r[2], y2 = r[3];
            float w = x2 - x1, h = y2 - y1;
            float cx = x1 + 0.5f * w, cy = y1 + 0.5f * h;
            float dx = d[0], dy = d[1];
            float dw = fminf(fmaxf(d[2], -MAX_RATIO), MAX_RATIO);
            float dh = fminf(fmaxf(d[3], -MAX_RATIO), MAX_RATIO);
            float pw = w * expf(dw), ph = h * expf(dh);
            float pcx = cx + dx * w, pcy = cy + dy * h;
            box0 = pcx - 0.5f * pw; box1 = pcy - 0.5f * ph;
            box2 = pcx + 0.5f * pw; box3 = pcy + 0.5f * ph;
        } else {
            score = -1.0f; cf = 0.0f; vld = 0u; box0 = box1 = box2 = box3 = 0.0f;
        }
        size_t o = (size_t)b * KK + kk;
        tscore[o] = score; tcls[o] = cf; tvalid[o] = vld;
        float off = cf * CLS_OFF;
        tbox[o*4+0] = box0; tbox[o*4+1] = box1; tbox[o*4+2] = box2; tbox[o*4+3] = box3;
        tobox[o*4+0] = box0 + off; tobox[o*4+1] = box1 + off;
        tobox[o*4+2] = box2 + off; tobox[o*4+3] = box3 + off;
    }
}

// ---------------- IoU > thr bitmask, lower-triangle only, maskT[b][w][i] ----------------
__global__ void iou_mask(const float* __restrict__ obox, u64* __restrict__ maskT) {
    __shared__ float jb[64][4];
    int b = blockIdx.z, ib = blockIdx.x, jbk = blockIdx.y;
    if (jbk > ib) return;           // nms_scan never reads these words
    int t = threadIdx.x;
    int j0 = jbk * 64;
    int jg = j0 + t;
    if (jg < KK) {
        const float* p = obox + ((size_t)b * KK + jg) * 4;
        jb[t][0] = p[0]; jb[t][1] = p[1]; jb[t][2] = p[2]; jb[t][3] = p[3];
    } else {
        jb[t][0] = 0; jb[t][1] = 0; jb[t][2] = 0; jb[t][3] = 0;
    }
    __syncthreads();
    int i = ib * 64 + t;
    if (i >= KK) return;
    const float* p = obox + ((size_t)b * KK + i) * 4;
    float x1 = p[0], y1 = p[1], x2 = p[2], y2 = p[3];
    float ai = (x2 - x1) * (y2 - y1);
    u64 bits = 0;
    int jmax = min(64, KK - j0);
    for (int jj = 0; jj < jmax; ++jj) {
        float bx1 = jb[jj][0], by1 = jb[jj][1], bx2 = jb[jj][2], by2 = jb[jj][3];
        float aj = (bx2 - bx1) * (by2 - by1);
        float iw = fmaxf(fminf(x2, bx2) - fmaxf(x1, bx1), 0.0f);
        float ih = fmaxf(fminf(y2, by2) - fmaxf(y1, by1), 0.0f);
        float inter = iw * ih;
        float iou = inter / (ai + aj - inter + 1e-9f);
        if (iou > NMS_THR) bits |= (1ull << jj);
    }
    maskT[((size_t)b * NW + jbk) * KK + i] = bits;
}

// ---------------- blocked ballot fixed-point NMS + output ----------------
__global__ __launch_bounds__(256) void nms_scan(
    const u64* __restrict__ maskT, const u32* __restrict__ tvalid,
    const float* __restrict__ tbox, const float* __restrict__ tscore,
    const float* __restrict__ tcls, float* __restrict__ out) {
    __shared__ u64 skept[NW];
    int b = blockIdx.x;
    if (threadIdx.x < 64) {
        int lane = threadIdx.x;
        const u64* mT = maskT + (size_t)b * NW * KK;
        u64 keptW[NW];
        #pragma unroll
        for (int W = 0; W < NW; ++W) {
            int i = W * 64 + lane;
            bool inr = (i < KK);
            u64 row[NW];
            #pragma unroll
            for (int w = 0; w <= W; ++w)
                row[w] = inr ? mT[(size_t)w * KK + i] : 0ull;
            bool valid = inr && (tvalid[(size_t)b * KK + i] != 0u);
            u64 ext = 0;
            #pragma unroll
            for (int w = 0; w < W; ++w) ext |= keptW[w] & row[w];
            bool cand = valid && (ext == 0ull);
            u64 m_self = row[W] & ((1ull << lane) - 1ull);   // strictly-lower lanes
            u64 kept = __ballot(cand);
            while (true) {
                u64 k2 = __ballot(cand && ((kept & m_self) == 0ull));
                if (k2 == kept) break;
                kept = k2;
            }
            keptW[W] = kept;
            if (lane == 0) skept[W] = kept;
        }
    }
    __syncthreads();
    for (int kk = threadIdx.x; kk < KK; kk += blockDim.x) {
        size_t o = (size_t)b * KK + kk;
        float kf = (float)((skept[kk >> 6] >> (kk & 63)) & 1ull);
        float* op = out + o * 7;
        op[0] = tbox[o*4+0] * kf; op[1] = tbox[o*4+1] * kf;
        op[2] = tbox[o*4+2] * kf; op[3] = tbox[o*4+3] * kf;
        op[4] = tscore[o] * kf;   op[5] = tcls[o] * kf;   op[6] = kf;
    }
}

extern "C" void kernel_launch(void* const* d_in, const int* in_sizes, int n_in,
                              void* d_out, int out_size, void* d_ws, size_t ws_size,
                              hipStream_t stream) {
    const float* rois   = (const float*)d_in[0];   // (B,N,4)
    const float* scores = (const float*)d_in[1];   // (B*N,C,1,1) == (B, N*C)
    const float* reg    = (const float*)d_in[2];   // (B*N,4,1,1)
    float* out = (float*)d_out;

    char* ws = (char*)d_ws;
    u32* hist   = (u32*)(ws + WS_HIST);
    u32* gcnt   = (u32*)(ws + WS_GCNT);
    u64* gslice = (u64*)(ws + WS_GSLICE);
    float* tbox   = (float*)(ws + WS_TBOX);
    float* tobox  = (float*)(ws + WS_TOBOX);
    float* tscore = (float*)(ws + WS_TSCORE);
    float* tcls   = (float*)(ws + WS_TCLS);
    u32*   tvalid = (u32*)(ws + WS_TVALID);
    u64*   maskT  = (u64*)(ws + WS_MASK);

    hist0_pass<<<dim3(HB, BB), 1024, 0, stream>>>(scores, hist);

    gather2<<<dim3(GB, BB), 256, 0, stream>>>(scores, hist, gslice, gcnt);

    finalize<<<BB, 1024, 0, stream>>>(gslice, gcnt, hist, rois, reg,
                                      tbox, tobox, tscore, tcls, tvalid);

    iou_mask<<<dim3(16, 16, BB), 64, 0, stream>>>(tobox, maskT);

    nms_scan<<<BB, 256, 0, stream>>>(maskT, tvalid, tbox, tscore, tcls, out);
}